// Round 10
// baseline (2686.430 us; speedup 1.0000x reference)
//
#include <hip/hip_runtime.h>
#include <math.h>

#define T_LEN  512
#define B_SZ   64
#define E_DIM  128
#define H_DIM  256
#define G4     1024   // 4*H
#define K_TAGS 9
#define HP     268    // padded hlds row (shorts)

#define L2E      1.442695041f
#define TWO_L2E  2.885390082f

typedef __bf16 bf16x8 __attribute__((ext_vector_type(8)));
typedef float  f32x4  __attribute__((ext_vector_type(4)));

union BF8 { bf16x8 v; unsigned short u[8]; uint4 q; unsigned long long ull[2]; };

__device__ __forceinline__ unsigned short rne_bf16(float x) {
    unsigned int b = __float_as_uint(x);
    b += 0x7FFFu + ((b >> 16) & 1u);
    return (unsigned short)(b >> 16);
}
__device__ __forceinline__ float bf16_to_f(unsigned short u) {
    return __uint_as_float(((unsigned int)u) << 16);
}
__device__ __forceinline__ float rcpf_(float x)  { return __builtin_amdgcn_rcpf(x); }

// raw 2^(-x): log2e folded into the permuted weights; no inline asm (safe scheduling)
__device__ __forceinline__ float exp2n_(float x) {
#if __has_builtin(__builtin_amdgcn_exp2f)
    return __builtin_amdgcn_exp2f(-x);
#else
    return __expf(-0.6931471805599453f * x);   // 2^-x = e^(-x ln2)
#endif
}
// zp = L2E*z prescaled:  sigma(z) = 1/(1+2^-zp)
__device__ __forceinline__ float sig2_(float zp)  { return rcpf_(1.0f + exp2n_(zp)); }
// zp = 2*L2E*z prescaled: tanh(z) = 2/(1+2^-zp) - 1
__device__ __forceinline__ float tanh2_(float zp) { return fmaf(2.0f, rcpf_(1.0f + exp2n_(zp)), -1.0f); }

// unscaled versions (fallback kernel uses raw weights)
__device__ __forceinline__ float sigf(float x)   { return rcpf_(1.0f + __expf(-x)); }
__device__ __forceinline__ float tanhf_(float x) { return fmaf(2.0f, rcpf_(1.0f + __expf(-2.0f * x)), -1.0f); }

// ---------------- Kernel 0: fill logits with bd + lens ----------------
__global__ __launch_bounds__(256)
void init_kernel(const int* __restrict__ text, const float* __restrict__ bd,
                 float* __restrict__ out, int* __restrict__ ws_head) {
    const int b   = blockIdx.x;
    const int tid = threadIdx.x;
    float* lb = out + (size_t)b * (T_LEN * K_TAGS);
    for (int i = tid; i < T_LEN * K_TAGS; i += 256) lb[i] = bd[i % K_TAGS];
    int cnt = 0;
    for (int t = tid; t < T_LEN; t += 256) cnt += (text[b * T_LEN + t] != 0) ? 1 : 0;
    __shared__ int red[4];
    for (int off = 32; off > 0; off >>= 1) cnt += __shfl_down(cnt, off);
    if ((tid & 63) == 0) red[tid >> 6] = cnt;
    __syncthreads();
    if (tid == 0) {
        int c = red[0] + red[1] + red[2] + red[3];
        out[(size_t)B_SZ * T_LEN * K_TAGS + b] = (float)c;
        ws_head[b] = c;
    }
}

// ---------------- Kernel P: permute weights -> Uc, Wc (bf16 col-major), bperm ----------------
// col' = 4*u + g  <->  orig col = 256*g + u
// PRESCALE: gates i,f,o scaled by log2(e); gate g (cell) by 2*log2(e) so the
// recurrence can use raw v_exp_f32 (2^x) with no per-element mul.
__global__ __launch_bounds__(64)
void permute_kernel(const float* __restrict__ Wf, const float* __restrict__ Uf, const float* __restrict__ bf_,
                    const float* __restrict__ Wb, const float* __restrict__ Ub, const float* __restrict__ bb,
                    unsigned short* __restrict__ Uc, unsigned short* __restrict__ Wc,
                    float* __restrict__ bperm)
{
    const int colp = blockIdx.x;           // 0..1023
    const int dir  = blockIdx.y;           // 0..1
    const float* W = dir ? Wb : Wf;
    const float* U = dir ? Ub : Uf;
    const float* bs = dir ? bb : bf_;
    const int g = colp & 3, u = colp >> 2;
    const int oc = g * 256 + u;
    const float sc = (g == 2) ? TWO_L2E : L2E;
    const int t = threadIdx.x;
    for (int k = t; k < 256; k += 64)
        Uc[((size_t)dir * 1024 + colp) * 256 + k] = rne_bf16(sc * U[(size_t)k * G4 + oc]);
    for (int k = t; k < 128; k += 64)
        Wc[((size_t)dir * 1024 + colp) * 128 + k] = rne_bf16(sc * W[(size_t)k * G4 + oc]);
    if (t == 0) bperm[dir * 1024 + colp] = sc * bs[oc];
}

// ---------------- Kernel X: xw[dir][bq][t][quad][b16][4gates] = x_t @ W + bias (bf16) ----------------
__global__ __launch_bounds__(512)
void xw_kernel(const int* __restrict__ text, const float* __restrict__ emb,
               const unsigned short* __restrict__ Wc, const float* __restrict__ bperm,
               unsigned short* __restrict__ xwq)
{
    const int t   = blockIdx.x;
    const int dir = blockIdx.y;
    const int tid = threadIdx.x;
    const int w = tid >> 6, l = tid & 63, r = l & 15, q = l >> 4;

    __shared__ unsigned short xs[64][136];    // x_t bf16
    __shared__ unsigned short wl[256][136];   // W chunk bf16 col-major

    {
        const int b = tid >> 3, e0 = (tid & 7) * 16;
        const int tok = text[b * T_LEN + t];
        const float* er = emb + (size_t)tok * E_DIM + e0;
        #pragma unroll
        for (int jj = 0; jj < 16; ++jj) xs[b][e0 + jj] = rne_bf16(er[jj]);
    }

    for (int nc = 0; nc < 4; ++nc) {
        __syncthreads();
        for (int i = tid; i < 256 * 16; i += 512) {
            const int cc = i >> 4, k8 = (i & 15) * 8;
            *(uint4*)&wl[cc][k8] =
                *(const uint4*)&Wc[((size_t)dir * 1024 + 256 * nc + cc) * 128 + k8];
        }
        __syncthreads();

        #pragma unroll
        for (int mt = 0; mt < 2; ++mt) {
            const int ccol = 32 * w + 16 * mt + r;
            const float4 bb4 = *(const float4*)&bperm[dir * 1024 + 256 * nc + 32 * w + 16 * mt + 4 * q];
            f32x4 acc[4];
            #pragma unroll
            for (int nt = 0; nt < 4; ++nt) acc[nt] = (f32x4){bb4.x, bb4.y, bb4.z, bb4.w};
            #pragma unroll
            for (int ks = 0; ks < 4; ++ks) {
                BF8 af; af.q = *(const uint4*)&wl[ccol][32 * ks + 8 * q];
                #pragma unroll
                for (int nt = 0; nt < 4; ++nt) {
                    BF8 bfv; bfv.q = *(const uint4*)&xs[16 * nt + r][32 * ks + 8 * q];
                    acc[nt] = __builtin_amdgcn_mfma_f32_16x16x32_bf16(af.v, bfv.v, acc[nt], 0, 0, 0);
                }
            }
            #pragma unroll
            for (int nt = 0; nt < 4; ++nt) {
                const int quad = 64 * nc + 8 * w + 4 * mt + q;
                unsigned long long pv =
                      (unsigned long long)rne_bf16(acc[nt][0])
                    | ((unsigned long long)rne_bf16(acc[nt][1]) << 16)
                    | ((unsigned long long)rne_bf16(acc[nt][2]) << 32)
                    | ((unsigned long long)rne_bf16(acc[nt][3]) << 48);
                const size_t off = ((((size_t)dir * 4 + nt) * T_LEN + t) * 256 + quad) * 16 + r;
                *(unsigned long long*)&xwq[off * 4] = pv;
            }
        }
    }
}

// ---------------- Kernel R: batch-split U-resident recurrence (r4 body + A/B alias split) ----------------
// 8 blocks = (dir, bq). U split:
//   k=0..159   -> uf[8][5] fragments (AGPR-resident; r6/r8/r9: ANY extra live
//                 registers evict this preload -> 1.6-1.7x loss. ZERO new regs.)
//   k=160..223 -> ulds4 (128 KB LDS)
//   k=224..255 -> streamed from L1/L2 per gr (loop-invariant addrs)
// ROUND-10: test the r9 ALIAS THEORY at zero register cost. r4's serialization:
// hlds[Rb] reads vs hlds[Wn] writes have runtime parity -> compiler cannot
// disambiguate -> gr1's hfv ds_reads stay ordered after gr0's gate ds_writes,
// and in-order lgkm retirement serializes MFMA->gates->MFMA (measured: serial
// sum, MfmaUtil 34% + VALU 52% + idle). Fix: TWO DISTINCT __shared__ objects
// hldsA/hldsB referenced LITERALLY via a 2x-unrolled step (read A/write B,
// then read B/write A). Statically distinct objects -> scheduler may hoist
// gr1's h reads above gr0's gate writes -> phase overlap. Body is byte-for-
// byte r4's (per-gr hfv loads, xw at step top, single acc); only the buffer
// naming changes. Duplication is register-safe (r3 precedent: VGPR 128).
__global__ __launch_bounds__(512, 1)
void rec_kernel(const unsigned short* __restrict__ Uc,
                unsigned short* __restrict__ xwq)
{
    const int bx  = blockIdx.x;
    const int dir = bx >> 2, bq = bx & 3;
    const int tid = threadIdx.x;
    const int w = tid >> 6, l = tid & 63, r = l & 15, q = l >> 4;

    __shared__ uint4 ulds4[2][4][1024];          // U k=160..223 : 128 KB
    __shared__ unsigned short hldsA[16][HP];     // h parity A : ~8.6 KB
    __shared__ unsigned short hldsB[16][HP];     // h parity B : ~8.6 KB

    const unsigned short* ucb = Uc + (size_t)dir * 1024 * 256;

    // resident U fragments, k < 160 (DO NOT REMOVE -- r6 lesson)
    BF8 uf[8][5];
    #pragma unroll
    for (int nt = 0; nt < 8; ++nt) {
        const int colp = 128 * w + 16 * nt + r;
        #pragma unroll
        for (int ks = 0; ks < 5; ++ks)
            uf[nt][ks].q = *(const uint4*)&ucb[(size_t)colp * 256 + 32 * ks + 8 * q];
    }
    // stage U k=160..223 as [s][q][colp] uint4
    for (int i = tid; i < 8192; i += 512) {
        const int s = i >> 12, qq = (i >> 10) & 3, colp = i & 1023;
        ulds4[s][qq][colp] =
            *(const uint4*)&ucb[(size_t)colp * 256 + 160 + 32 * s + 8 * qq];
    }
    {
        unsigned int* hz = (unsigned int*)&hldsA[0][0];
        for (int i = tid; i < 16 * HP / 2; i += 512) hz[i] = 0u;
        unsigned int* hz2 = (unsigned int*)&hldsB[0][0];
        for (int i = tid; i < 16 * HP / 2; i += 512) hz2[i] = 0u;
    }
    float creg[8] = {0.f, 0.f, 0.f, 0.f, 0.f, 0.f, 0.f, 0.f};
    uint4 hpack = make_uint4(0, 0, 0, 0);        // packed h_t (8 bf16)
    unsigned short* xwb = xwq + (size_t)(dir * 4 + bq) * T_LEN * 16384;
    const size_t hoff = (size_t)(((w * 4 + q) * 16 + r) * 8);   // h layout [w][q][r][nt]
    __syncthreads();

// r4's step body verbatim; SRC/DST are LITERAL distinct __shared__ arrays.
#define REC_STEP(T, SRC, DST)                                                       \
  {                                                                                 \
    if ((T) > 0)                                                                    \
        *(uint4*)&xwb[(size_t)((T) - 1) * 16384 + hoff] = hpack;                    \
    uint2 xwv[8];                                                                   \
    _Pragma("unroll")                                                               \
    for (int nt = 0; nt < 8; ++nt) {                                                \
        const int quad = 32 * w + 4 * nt + q;                                       \
        xwv[nt] = *(const uint2*)&xwb[(size_t)(T) * 16384                           \
                                      + (size_t)(quad * 16 + r) * 4];               \
    }                                                                               \
    _Pragma("unroll")                                                               \
    for (int gr = 0; gr < 2; ++gr) {                                                \
        BF8 u7[4];                                                                  \
        _Pragma("unroll")                                                           \
        for (int nn = 0; nn < 4; ++nn) {                                            \
            const int colp = 128 * w + 16 * (4 * gr + nn) + r;                      \
            u7[nn].q = *(const uint4*)&ucb[(size_t)colp * 256 + 224 + 8 * q];       \
        }                                                                           \
        f32x4 acc[4];                                                               \
        _Pragma("unroll")                                                           \
        for (int nn = 0; nn < 4; ++nn) acc[nn] = (f32x4){0.f, 0.f, 0.f, 0.f};       \
        _Pragma("unroll")                                                           \
        for (int ks = 0; ks < 5; ++ks) {                                            \
            BF8 hfv; hfv.q = *(const uint4*)&SRC[r][32 * ks + 8 * q];               \
            _Pragma("unroll")                                                       \
            for (int nn = 0; nn < 4; ++nn)                                          \
                acc[nn] = __builtin_amdgcn_mfma_f32_16x16x32_bf16(                  \
                    uf[4 * gr + nn][ks].v, hfv.v, acc[nn], 0, 0, 0);                \
        }                                                                           \
        _Pragma("unroll")                                                           \
        for (int ks = 5; ks < 7; ++ks) {                                            \
            BF8 hfv; hfv.q = *(const uint4*)&SRC[r][32 * ks + 8 * q];               \
            _Pragma("unroll")                                                       \
            for (int nn = 0; nn < 4; ++nn) {                                        \
                const int colp = 128 * w + 16 * (4 * gr + nn) + r;                  \
                BF8 uv; uv.q = ulds4[ks - 5][q][colp];                              \
                acc[nn] = __builtin_amdgcn_mfma_f32_16x16x32_bf16(                  \
                    uv.v, hfv.v, acc[nn], 0, 0, 0);                                 \
            }                                                                       \
        }                                                                           \
        {                                                                           \
            BF8 hfv; hfv.q = *(const uint4*)&SRC[r][224 + 8 * q];                   \
            _Pragma("unroll")                                                       \
            for (int nn = 0; nn < 4; ++nn)                                          \
                acc[nn] = __builtin_amdgcn_mfma_f32_16x16x32_bf16(                  \
                    u7[nn].v, hfv.v, acc[nn], 0, 0, 0);                             \
        }                                                                           \
        unsigned int p0 = 0, p1 = 0;                                                \
        _Pragma("unroll")                                                           \
        for (int nn = 0; nn < 4; ++nn) {                                            \
            const int nt = 4 * gr + nn;                                             \
            const uint2 xv = xwv[4 * gr + nn];                                      \
            const float z0 = acc[nn][0] + bf16_to_f((unsigned short)(xv.x & 0xffff)); \
            const float z1 = acc[nn][1] + bf16_to_f((unsigned short)(xv.x >> 16));  \
            const float z2 = acc[nn][2] + bf16_to_f((unsigned short)(xv.y & 0xffff)); \
            const float z3 = acc[nn][3] + bf16_to_f((unsigned short)(xv.y >> 16));  \
            const float c = sig2_(z1) * creg[nt] + sig2_(z0) * tanh2_(z2);          \
            const float h = sig2_(z3) * tanh2_(c * TWO_L2E);                        \
            creg[nt] = c;                                                           \
            const unsigned short hh = rne_bf16(h);                                  \
            DST[r][32 * w + 4 * nt + q] = hh;                                       \
            if (nn < 2) p0 |= ((unsigned int)hh) << (16 * (nn & 1));                \
            else        p1 |= ((unsigned int)hh) << (16 * (nn & 1));                \
        }                                                                           \
        if (gr == 0) { hpack.x = p0; hpack.y = p1; }                                \
        else         { hpack.z = p0; hpack.w = p1; }                                \
    }                                                                               \
    __syncthreads();                                                                \
  }

    for (int t = 0; t < T_LEN; t += 2) {
        REC_STEP(t,     hldsA, hldsB);
        REC_STEP(t + 1, hldsB, hldsA);
    }
#undef REC_STEP

    // epilogue: store h_{T-1}
    *(uint4*)&xwb[(size_t)(T_LEN - 1) * 16384 + hoff] = hpack;
}

// ---------------- Kernel L: logits = [hf;hb] @ Wd + bd ----------------
// h layout in slot s: shorts[((w*4+q)*16 + b16)*8 + nt] = h[unit 32w+4nt+q].
// dir0 slot s = position s; dir1 slot s = position T-1-s.
__global__ __launch_bounds__(256)
void logits_kernel(const unsigned short* __restrict__ xwq,
                   const float* __restrict__ Wd, const float* __restrict__ bd,
                   float* __restrict__ out)
{
    __shared__ float wdl[2 * H_DIM * K_TAGS];   // 18 KB
    __shared__ float bdl[16];
    const int tid = threadIdx.x;
    for (int i = tid; i < 2 * H_DIM * K_TAGS; i += 256) wdl[i] = Wd[i];
    if (tid < K_TAGS) bdl[tid] = bd[tid];
    __syncthreads();

    const int flat = blockIdx.x * 256 + tid;    // 0..32767
    const int b = flat >> 9, t = flat & (T_LEN - 1);
    const int bq = b >> 4, bl = b & 15;
    const unsigned short* hf = xwq + ((size_t)(0 * 4 + bq) * T_LEN + t) * 16384;
    const unsigned short* hb = xwq + ((size_t)(1 * 4 + bq) * T_LEN + (T_LEN - 1 - t)) * 16384;

    float a[K_TAGS];
    #pragma unroll
    for (int k = 0; k < K_TAGS; ++k) a[k] = bdl[k];
    #pragma unroll
    for (int w = 0; w < 8; ++w) {
        #pragma unroll
        for (int q = 0; q < 4; ++q) {
            BF8 hv; hv.q = *(const uint4*)&hf[((w * 4 + q) * 16 + bl) * 8];
            #pragma unroll
            for (int nt = 0; nt < 8; ++nt) {
                const float h = bf16_to_f(hv.u[nt]);
                const float* wr = &wdl[(32 * w + 4 * nt + q) * K_TAGS];
                #pragma unroll
                for (int k = 0; k < K_TAGS; ++k) a[k] = fmaf(h, wr[k], a[k]);
            }
        }
    }
    #pragma unroll
    for (int w = 0; w < 8; ++w) {
        #pragma unroll
        for (int q = 0; q < 4; ++q) {
            BF8 hv; hv.q = *(const uint4*)&hb[((w * 4 + q) * 16 + bl) * 8];
            #pragma unroll
            for (int nt = 0; nt < 8; ++nt) {
                const float h = bf16_to_f(hv.u[nt]);
                const float* wr = &wdl[(H_DIM + 32 * w + 4 * nt + q) * K_TAGS];
                #pragma unroll
                for (int k = 0; k < K_TAGS; ++k) a[k] = fmaf(h, wr[k], a[k]);
            }
        }
    }
    float* ob = out + ((size_t)b * T_LEN + t) * K_TAGS;
    #pragma unroll
    for (int k = 0; k < K_TAGS; ++k) ob[k] = a[k];
}

// ---------------- Fallback (ws too small): R2 fp32 persistent BiLSTM, proven ----------------
__global__ __launch_bounds__(1024)
void lstm_fb(const int* __restrict__ text, const float* __restrict__ emb,
             const float* __restrict__ Wf, const float* __restrict__ Uf, const float* __restrict__ bf_,
             const float* __restrict__ Wb, const float* __restrict__ Ub, const float* __restrict__ bb,
             const float* __restrict__ Wd, float* __restrict__ out)
{
    const int bi   = blockIdx.x;
    const int d    = bi >> 5;
    const int pair = bi & 31;
    const int tid  = threadIdx.x;
    const int kc   = tid >> 8;
    const int idx  = tid & 255;

    const float* Wp = d ? Wb : Wf;
    const float* Up = d ? Ub : Uf;
    const float* bp = d ? bb : bf_;

    __shared__ __align__(16) float2 vbuf[2][384];
    __shared__ float  cspf[2][H_DIM];
    __shared__ __align__(16) float2 zp[16][256];
    __shared__ float  wdl[H_DIM * K_TAGS];
    __shared__ float  bpl[G4];

    for (int i = tid; i < H_DIM * K_TAGS; i += 1024) wdl[i] = Wd[d * H_DIM * K_TAGS + i];
    for (int i = tid; i < G4; i += 1024) bpl[i] = bp[i];
    if (tid < H_DIM) {
        vbuf[0][E_DIM + tid] = make_float2(0.0f, 0.0f);
        cspf[0][tid] = 0.0f;
        cspf[1][tid] = 0.0f;
    }
    __syncthreads();

    int cur = 0;
    for (int t = 0; t < T_LEN; ++t) {
        const int p = d ? (T_LEN - 1 - t) : t;
        const int nxt = cur ^ 1;

        if (tid < E_DIM) {
            const int tok0 = text[(pair * 2 + 0) * T_LEN + p];
            const int tok1 = text[(pair * 2 + 1) * T_LEN + p];
            vbuf[cur][tid] = make_float2(emb[(size_t)tok0 * E_DIM + tid],
                                         emb[(size_t)tok1 * E_DIM + tid]);
        }
        __syncthreads();

        {
            float2 a0 = make_float2(0.f, 0.f), a1 = a0, a2 = a0, a3 = a0;
            const int k0 = kc * 96;
            const float* wp = Wp + (size_t)k0 * G4 + 4 * idx;
            const float* up = Up + ((long)k0 - E_DIM) * G4 + 4 * idx;
            const float2* __restrict__ vb = vbuf[cur];
            #pragma unroll 8
            for (int i = 0; i < 96; ++i) {
                const int k = k0 + i;
                const float4 wv = *(const float4*)((k < E_DIM) ? wp : up);
                const float2 v = vb[k];
                a0.x = fmaf(wv.x, v.x, a0.x); a0.y = fmaf(wv.x, v.y, a0.y);
                a1.x = fmaf(wv.y, v.x, a1.x); a1.y = fmaf(wv.y, v.y, a1.y);
                a2.x = fmaf(wv.z, v.x, a2.x); a2.y = fmaf(wv.z, v.y, a2.y);
                a3.x = fmaf(wv.w, v.x, a3.x); a3.y = fmaf(wv.w, v.y, a3.y);
                wp += G4; up += G4;
            }
            zp[kc * 4 + 0][idx] = a0;
            zp[kc * 4 + 1][idx] = a1;
            zp[kc * 4 + 2][idx] = a2;
            zp[kc * 4 + 3][idx] = a3;
        }
        __syncthreads();

        if (tid < 512) {
            const int b = tid >> 8, u = tid & 255;
            const int j = u & 3, rr = u >> 2;
            float zs[4];
            #pragma unroll
            for (int g = 0; g < 4; ++g) {
                float s = bpl[g * 256 + u];
                #pragma unroll
                for (int c = 0; c < 4; ++c)
                    s += ((const float*)&zp[c * 4 + j][g * 64 + rr])[b];
                zs[g] = s;
            }
            const float co = cspf[b][u];
            const float cg = tanhf_(zs[2]);
            const float cn = sigf(zs[1]) * co + sigf(zs[0]) * cg;
            const float h  = sigf(zs[3]) * tanhf_(cn);
            cspf[b][u] = cn;
            ((float*)&vbuf[nxt][E_DIM + u])[b] = h;
        }
        __syncthreads();

        {
            const int w = tid >> 6, l = tid & 63;
            const float2* __restrict__ hb = vbuf[nxt] + E_DIM;
            for (int tau = w; tau < 2 * K_TAGS; tau += 16) {
                const int gb = tau / K_TAGS, k = tau - K_TAGS * gb;
                float v = 0.0f;
                #pragma unroll
                for (int m = 0; m < 4; ++m) {
                    const int col = l + 64 * m;
                    const float hv = ((const float*)&hb[col])[gb];
                    v += hv * wdl[col * K_TAGS + k];
                }
                for (int off = 32; off > 0; off >>= 1) v += __shfl_down(v, off);
                if (l == 0)
                    atomicAdd(&out[((size_t)(pair * 2 + gb) * T_LEN + p) * K_TAGS + k], v);
            }
        }
        cur = nxt;
    }
}

// ---------------- Kernel 2: CRF log-likelihood ----------------
__global__ __launch_bounds__(64)
void crf_kernel(const int* __restrict__ labels, const float* __restrict__ trans,
                const int* __restrict__ lens_ws, float* __restrict__ out)
{
    const int b    = blockIdx.x;
    const int lane = threadIdx.x;
    const int len  = lens_ws[b];
    const float* lb = out + (size_t)b * (T_LEN * K_TAGS);
    const int* lab  = labels + (size_t)b * T_LEN;

    float ub = 0.0f;
    for (int t = lane; t < T_LEN; t += 64) {
        if (t < len)            ub += lb[t * K_TAGS + lab[t]];
        if (t >= 1 && t < len)  ub += trans[lab[t - 1] * K_TAGS + lab[t]];
    }
    for (int off = 32; off > 0; off >>= 1) ub += __shfl_down(ub, off);

    float trc[K_TAGS];
    #pragma unroll
    for (int i = 0; i < K_TAGS; ++i)
        trc[i] = (lane < K_TAGS) ? trans[i * K_TAGS + lane] : 0.0f;
    const int kk = (lane < K_TAGS) ? lane : 0;
    float alpha = (lane < K_TAGS) ? lb[lane] : 0.0f;

    for (int t = 1; t < len; ++t) {
        float v[K_TAGS];
        float m = -1e30f;
        #pragma unroll
        for (int i = 0; i < K_TAGS; ++i) {
            float ai = __shfl(alpha, i);
            v[i] = ai + trc[i];
            m = fmaxf(m, v[i]);
        }
        float s = 0.0f;
        #pragma unroll
        for (int i = 0; i < K_TAGS; ++i) s += __expf(v[i] - m);
        float na = m + __logf(s) + lb[t * K_TAGS + kk];
        if (lane < K_TAGS) alpha = na;
    }

    float m2 = -1e30f;
    #pragma unroll
    for (int i = 0; i < K_TAGS; ++i) m2 = fmaxf(m2, __shfl(alpha, i));
    float s2 = 0.0f;
    #pragma unroll
    for (int i = 0; i < K_TAGS; ++i) s2 += __expf(__shfl(alpha, i) - m2);
    float logn = m2 + __logf(s2);

    if (lane == 0)
        out[(size_t)B_SZ * T_LEN * K_TAGS + B_SZ + b] = ub - logn;
}

extern "C" void kernel_launch(void* const* d_in, const int* in_sizes, int n_in,
                              void* d_out, int out_size, void* d_ws, size_t ws_size,
                              hipStream_t stream) {
    const int*   text   = (const int*)d_in[0];
    const int*   labels = (const int*)d_in[1];
    const float* emb    = (const float*)d_in[2];
    const float* Wf     = (const float*)d_in[3];
    const float* Uf     = (const float*)d_in[4];
    const float* bf_    = (const float*)d_in[5];
    const float* Wb     = (const float*)d_in[6];
    const float* Ub     = (const float*)d_in[7];
    const float* bb     = (const float*)d_in[8];
    const float* Wd     = (const float*)d_in[9];
    const float* bd     = (const float*)d_in[10];
    const float* trans  = (const float*)d_in[11];
    float* out = (float*)d_out;

    int* ws_head = (int*)d_ws;
    int* lens_ws = ws_head;

    unsigned short* Uc    = (unsigned short*)((char*)d_ws + 4096);            // 1 MB
    unsigned short* Wc    = (unsigned short*)((char*)d_ws + 4096 + 1048576);  // 512 KB
    float*          bperm = (float*)((char*)d_ws + 4096 + 1048576 + 524288);  // 8 KB
    unsigned short* xwq   = (unsigned short*)((char*)d_ws + 2097152);         // 128 MB (xw + hseq)
    const size_t need = 2097152 + (size_t)2 * 4 * T_LEN * 16384 * 2;

    init_kernel<<<B_SZ, 256, 0, stream>>>(text, bd, out, ws_head);
    if (ws_size >= need) {
        permute_kernel<<<dim3(1024, 2), 64, 0, stream>>>(Wf, Uf, bf_, Wb, Ub, bb, Uc, Wc, bperm);
        xw_kernel<<<dim3(T_LEN, 2), 512, 0, stream>>>(text, emb, Wc, bperm, xwq);
        rec_kernel<<<8, 512, 0, stream>>>(Uc, xwq);
        logits_kernel<<<(B_SZ * T_LEN) / 256, 256, 0, stream>>>(xwq, Wd, bd, out);
    } else {
        lstm_fb<<<64, 1024, 0, stream>>>(text, emb, Wf, Uf, bf_, Wb, Ub, bb, Wd, out);
    }
    crf_kernel<<<B_SZ, 64, 0, stream>>>(labels, trans, lens_ws, out);
}

// Round 11
// 1510.724 us; speedup vs baseline: 1.7782x; 1.7782x over previous
//
#include <hip/hip_runtime.h>
#include <math.h>

#define T_LEN  512
#define B_SZ   64
#define E_DIM  128
#define H_DIM  256
#define G4     1024   // 4*H
#define K_TAGS 9
#define HP     268    // padded hlds row (shorts)

#define L2E      1.442695041f
#define TWO_L2E  2.885390082f

typedef __bf16 bf16x8 __attribute__((ext_vector_type(8)));
typedef float  f32x4  __attribute__((ext_vector_type(4)));

union BF8 { bf16x8 v; unsigned short u[8]; uint4 q; unsigned long long ull[2]; };

__device__ __forceinline__ unsigned short rne_bf16(float x) {
    unsigned int b = __float_as_uint(x);
    b += 0x7FFFu + ((b >> 16) & 1u);
    return (unsigned short)(b >> 16);
}
__device__ __forceinline__ float bf16_to_f(unsigned short u) {
    return __uint_as_float(((unsigned int)u) << 16);
}
__device__ __forceinline__ float rcpf_(float x)  { return __builtin_amdgcn_rcpf(x); }

// raw 2^(-x): log2e folded into the permuted weights; no inline asm (safe scheduling)
__device__ __forceinline__ float exp2n_(float x) {
#if __has_builtin(__builtin_amdgcn_exp2f)
    return __builtin_amdgcn_exp2f(-x);
#else
    return __expf(-0.6931471805599453f * x);   // 2^-x = e^(-x ln2)
#endif
}
// zp = L2E*z prescaled:  sigma(z) = 1/(1+2^-zp)
__device__ __forceinline__ float sig2_(float zp)  { return rcpf_(1.0f + exp2n_(zp)); }
// zp = 2*L2E*z prescaled: tanh(z) = 2/(1+2^-zp) - 1
__device__ __forceinline__ float tanh2_(float zp) { return fmaf(2.0f, rcpf_(1.0f + exp2n_(zp)), -1.0f); }

// unscaled versions (fallback kernel uses raw weights)
__device__ __forceinline__ float sigf(float x)   { return rcpf_(1.0f + __expf(-x)); }
__device__ __forceinline__ float tanhf_(float x) { return fmaf(2.0f, rcpf_(1.0f + __expf(-2.0f * x)), -1.0f); }

// ---------------- Kernel 0: fill logits with bd + lens ----------------
__global__ __launch_bounds__(256)
void init_kernel(const int* __restrict__ text, const float* __restrict__ bd,
                 float* __restrict__ out, int* __restrict__ ws_head) {
    const int b   = blockIdx.x;
    const int tid = threadIdx.x;
    float* lb = out + (size_t)b * (T_LEN * K_TAGS);
    for (int i = tid; i < T_LEN * K_TAGS; i += 256) lb[i] = bd[i % K_TAGS];
    int cnt = 0;
    for (int t = tid; t < T_LEN; t += 256) cnt += (text[b * T_LEN + t] != 0) ? 1 : 0;
    __shared__ int red[4];
    for (int off = 32; off > 0; off >>= 1) cnt += __shfl_down(cnt, off);
    if ((tid & 63) == 0) red[tid >> 6] = cnt;
    __syncthreads();
    if (tid == 0) {
        int c = red[0] + red[1] + red[2] + red[3];
        out[(size_t)B_SZ * T_LEN * K_TAGS + b] = (float)c;
        ws_head[b] = c;
    }
}

// ---------------- Kernel P: permute weights -> Uc, Wc (bf16 col-major), bperm ----------------
// col' = 4*u + g  <->  orig col = 256*g + u
// PRESCALE: gates i,f,o scaled by log2(e); gate g (cell) by 2*log2(e) so the
// recurrence can use raw v_exp_f32 (2^x) with no per-element mul.
__global__ __launch_bounds__(64)
void permute_kernel(const float* __restrict__ Wf, const float* __restrict__ Uf, const float* __restrict__ bf_,
                    const float* __restrict__ Wb, const float* __restrict__ Ub, const float* __restrict__ bb,
                    unsigned short* __restrict__ Uc, unsigned short* __restrict__ Wc,
                    float* __restrict__ bperm)
{
    const int colp = blockIdx.x;           // 0..1023
    const int dir  = blockIdx.y;           // 0..1
    const float* W = dir ? Wb : Wf;
    const float* U = dir ? Ub : Uf;
    const float* bs = dir ? bb : bf_;
    const int g = colp & 3, u = colp >> 2;
    const int oc = g * 256 + u;
    const float sc = (g == 2) ? TWO_L2E : L2E;
    const int t = threadIdx.x;
    for (int k = t; k < 256; k += 64)
        Uc[((size_t)dir * 1024 + colp) * 256 + k] = rne_bf16(sc * U[(size_t)k * G4 + oc]);
    for (int k = t; k < 128; k += 64)
        Wc[((size_t)dir * 1024 + colp) * 128 + k] = rne_bf16(sc * W[(size_t)k * G4 + oc]);
    if (t == 0) bperm[dir * 1024 + colp] = sc * bs[oc];
}

// ---------------- Kernel X: xw[dir][bq][t][quad][b16][4gates] = x_t @ W + bias (bf16) ----------------
__global__ __launch_bounds__(512)
void xw_kernel(const int* __restrict__ text, const float* __restrict__ emb,
               const unsigned short* __restrict__ Wc, const float* __restrict__ bperm,
               unsigned short* __restrict__ xwq)
{
    const int t   = blockIdx.x;
    const int dir = blockIdx.y;
    const int tid = threadIdx.x;
    const int w = tid >> 6, l = tid & 63, r = l & 15, q = l >> 4;

    __shared__ unsigned short xs[64][136];    // x_t bf16
    __shared__ unsigned short wl[256][136];   // W chunk bf16 col-major

    {
        const int b = tid >> 3, e0 = (tid & 7) * 16;
        const int tok = text[b * T_LEN + t];
        const float* er = emb + (size_t)tok * E_DIM + e0;
        #pragma unroll
        for (int jj = 0; jj < 16; ++jj) xs[b][e0 + jj] = rne_bf16(er[jj]);
    }

    for (int nc = 0; nc < 4; ++nc) {
        __syncthreads();
        for (int i = tid; i < 256 * 16; i += 512) {
            const int cc = i >> 4, k8 = (i & 15) * 8;
            *(uint4*)&wl[cc][k8] =
                *(const uint4*)&Wc[((size_t)dir * 1024 + 256 * nc + cc) * 128 + k8];
        }
        __syncthreads();

        #pragma unroll
        for (int mt = 0; mt < 2; ++mt) {
            const int ccol = 32 * w + 16 * mt + r;
            const float4 bb4 = *(const float4*)&bperm[dir * 1024 + 256 * nc + 32 * w + 16 * mt + 4 * q];
            f32x4 acc[4];
            #pragma unroll
            for (int nt = 0; nt < 4; ++nt) acc[nt] = (f32x4){bb4.x, bb4.y, bb4.z, bb4.w};
            #pragma unroll
            for (int ks = 0; ks < 4; ++ks) {
                BF8 af; af.q = *(const uint4*)&wl[ccol][32 * ks + 8 * q];
                #pragma unroll
                for (int nt = 0; nt < 4; ++nt) {
                    BF8 bfv; bfv.q = *(const uint4*)&xs[16 * nt + r][32 * ks + 8 * q];
                    acc[nt] = __builtin_amdgcn_mfma_f32_16x16x32_bf16(af.v, bfv.v, acc[nt], 0, 0, 0);
                }
            }
            #pragma unroll
            for (int nt = 0; nt < 4; ++nt) {
                const int quad = 64 * nc + 8 * w + 4 * mt + q;
                unsigned long long pv =
                      (unsigned long long)rne_bf16(acc[nt][0])
                    | ((unsigned long long)rne_bf16(acc[nt][1]) << 16)
                    | ((unsigned long long)rne_bf16(acc[nt][2]) << 32)
                    | ((unsigned long long)rne_bf16(acc[nt][3]) << 48);
                const size_t off = ((((size_t)dir * 4 + nt) * T_LEN + t) * 256 + quad) * 16 + r;
                *(unsigned long long*)&xwq[off * 4] = pv;
            }
        }
    }
}

// ---------------- Kernel R: batch-split U-resident recurrence (PROVEN 1279us -- round-4 verbatim) ----------------
// 8 blocks = (dir, bq). U split:
//   k=0..159   -> uf[8][5] fragments (AGPR half of the unified file; CSV VGPR=128
//                 shows arch VGPRs only). r6/r8/r9: evicting this costs 1.6-1.7x.
//   k=160..223 -> ulds4 (128 KB LDS)
//   k=224..255 -> streamed from L1/L2 per gr (loop-invariant addrs)
// FINAL STATE. Overlap-attempt ledger (all reverted):
//   r5  body duplication (phase inversion)  -> scratch spill, -47%
//   r6  hreg hoist replacing uf preload     -> uf eviction,  -70%
//   r7  s_setprio wave asymmetry            -> exactly null
//   r8  merged MFMA phase, split acc        -> uf eviction,  -80%
//   r9  chain-major pipeline + hreg         -> uf eviction,  -59%
//   r10 A/B LDS split + 2x-unroll           -> scratch spill, -93%
// Conclusion: the 256-reg/wave unified budget is exactly saturated by
// uf[8][5]+working set. Any source-level freedom that would let the scheduler
// overlap the MFMA phase (2.4k cyc/SIMD/step) with the gate VALU/trans phase
// (3.1k cyc) costs live registers, and one evicted uf fragment costs more than
// full overlap would gain. Step time = serial sum + barrier ~= 6k cyc; this is
// the structural floor of the 8-block batch-split decomposition on gfx950.
__global__ __launch_bounds__(512, 1)
void rec_kernel(const unsigned short* __restrict__ Uc,
                unsigned short* __restrict__ xwq)
{
    const int bx  = blockIdx.x;
    const int dir = bx >> 2, bq = bx & 3;
    const int tid = threadIdx.x;
    const int w = tid >> 6, l = tid & 63, r = l & 15, q = l >> 4;

    __shared__ uint4 ulds4[2][4][1024];          // U k=160..223 : 128 KB
    __shared__ unsigned short hlds[2][16][HP];   // [parity][batch][unit] : ~17 KB

    const unsigned short* ucb = Uc + (size_t)dir * 1024 * 256;

    // resident U fragments, k < 160
    BF8 uf[8][5];
    #pragma unroll
    for (int nt = 0; nt < 8; ++nt) {
        const int colp = 128 * w + 16 * nt + r;
        #pragma unroll
        for (int ks = 0; ks < 5; ++ks)
            uf[nt][ks].q = *(const uint4*)&ucb[(size_t)colp * 256 + 32 * ks + 8 * q];
    }
    // stage U k=160..223 as [s][q][colp] uint4
    for (int i = tid; i < 8192; i += 512) {
        const int s = i >> 12, qq = (i >> 10) & 3, colp = i & 1023;
        ulds4[s][qq][colp] =
            *(const uint4*)&ucb[(size_t)colp * 256 + 160 + 32 * s + 8 * qq];
    }
    {
        unsigned int* hz = (unsigned int*)&hlds[0][0][0];
        for (int i = tid; i < 16 * HP / 2; i += 512) hz[i] = 0u;
    }
    float creg[8] = {0.f, 0.f, 0.f, 0.f, 0.f, 0.f, 0.f, 0.f};
    uint4 hpack = make_uint4(0, 0, 0, 0);        // packed h_t (8 bf16)
    unsigned short* xwb = xwq + (size_t)(dir * 4 + bq) * T_LEN * 16384;
    const size_t hoff = (size_t)(((w * 4 + q) * 16 + r) * 8);   // h layout [w][q][r][nt]
    __syncthreads();

    for (int t = 0; t < T_LEN; ++t) {
        const int Rb = t & 1, Wn = Rb ^ 1;

        // publish h_{t-1} (from regs) into consumed slot t-1; barrier-safe
        if (t > 0)
            *(uint4*)&xwb[(size_t)(t - 1) * 16384 + hoff] = hpack;

        // all 8 xw loads for this step, issued together at the step top
        // (consumed in-step at the gates; gr=1's values get ~a full gr of cover)
        uint2 xwv[8];
        #pragma unroll
        for (int nt = 0; nt < 8; ++nt) {
            const int quad = 32 * w + 4 * nt + q;
            xwv[nt] = *(const uint2*)&xwb[(size_t)t * 16384 + (size_t)(quad * 16 + r) * 4];
        }

        #pragma unroll
        for (int gr = 0; gr < 2; ++gr) {
            // per-gr streamed U k=224..255 (L1/L2, loop-invariant addrs)
            BF8 u7[4];
            #pragma unroll
            for (int nn = 0; nn < 4; ++nn) {
                const int colp = 128 * w + 16 * (4 * gr + nn) + r;
                u7[nn].q = *(const uint4*)&ucb[(size_t)colp * 256 + 224 + 8 * q];
            }

            f32x4 acc[4];
            #pragma unroll
            for (int nn = 0; nn < 4; ++nn) acc[nn] = (f32x4){0.f, 0.f, 0.f, 0.f};
            #pragma unroll
            for (int ks = 0; ks < 5; ++ks) {
                BF8 hfv; hfv.q = *(const uint4*)&hlds[Rb][r][32 * ks + 8 * q];
                #pragma unroll
                for (int nn = 0; nn < 4; ++nn)
                    acc[nn] = __builtin_amdgcn_mfma_f32_16x16x32_bf16(
                        uf[4 * gr + nn][ks].v, hfv.v, acc[nn], 0, 0, 0);
            }
            #pragma unroll
            for (int ks = 5; ks < 7; ++ks) {
                BF8 hfv; hfv.q = *(const uint4*)&hlds[Rb][r][32 * ks + 8 * q];
                #pragma unroll
                for (int nn = 0; nn < 4; ++nn) {
                    const int colp = 128 * w + 16 * (4 * gr + nn) + r;
                    BF8 uv; uv.q = ulds4[ks - 5][q][colp];
                    acc[nn] = __builtin_amdgcn_mfma_f32_16x16x32_bf16(uv.v, hfv.v, acc[nn], 0, 0, 0);
                }
            }
            {   // ks = 7 from streamed registers
                BF8 hfv; hfv.q = *(const uint4*)&hlds[Rb][r][224 + 8 * q];
                #pragma unroll
                for (int nn = 0; nn < 4; ++nn)
                    acc[nn] = __builtin_amdgcn_mfma_f32_16x16x32_bf16(
                        u7[nn].v, hfv.v, acc[nn], 0, 0, 0);
            }

            // gates: acc[nn]+xw = prescaled {zi,zf,zg,zo} for (unit 32w+4(4gr+nn)+q, batch r)
            unsigned int p0 = 0, p1 = 0;
            #pragma unroll
            for (int nn = 0; nn < 4; ++nn) {
                const int nt = 4 * gr + nn;
                const uint2 xv = xwv[4 * gr + nn];
                const float z0 = acc[nn][0] + bf16_to_f((unsigned short)(xv.x & 0xffff));
                const float z1 = acc[nn][1] + bf16_to_f((unsigned short)(xv.x >> 16));
                const float z2 = acc[nn][2] + bf16_to_f((unsigned short)(xv.y & 0xffff));
                const float z3 = acc[nn][3] + bf16_to_f((unsigned short)(xv.y >> 16));
                const float c = sig2_(z1) * creg[nt] + sig2_(z0) * tanh2_(z2);
                const float h = sig2_(z3) * tanh2_(c * TWO_L2E);
                creg[nt] = c;
                const unsigned short hh = rne_bf16(h);
                hlds[Wn][r][32 * w + 4 * nt + q] = hh;
                if (nn < 2) p0 |= ((unsigned int)hh) << (16 * (nn & 1));
                else        p1 |= ((unsigned int)hh) << (16 * (nn & 1));
            }
            if (gr == 0) { hpack.x = p0; hpack.y = p1; }
            else         { hpack.z = p0; hpack.w = p1; }
        }
        __syncthreads();
    }
    // epilogue: store h_{T-1}
    *(uint4*)&xwb[(size_t)(T_LEN - 1) * 16384 + hoff] = hpack;
}

// ---------------- Kernel L: logits = [hf;hb] @ Wd + bd ----------------
// h layout in slot s: shorts[((w*4+q)*16 + b16)*8 + nt] = h[unit 32w+4nt+q].
// dir0 slot s = position s; dir1 slot s = position T-1-s.
__global__ __launch_bounds__(256)
void logits_kernel(const unsigned short* __restrict__ xwq,
                   const float* __restrict__ Wd, const float* __restrict__ bd,
                   float* __restrict__ out)
{
    __shared__ float wdl[2 * H_DIM * K_TAGS];   // 18 KB
    __shared__ float bdl[16];
    const int tid = threadIdx.x;
    for (int i = tid; i < 2 * H_DIM * K_TAGS; i += 256) wdl[i] = Wd[i];
    if (tid < K_TAGS) bdl[tid] = bd[tid];
    __syncthreads();

    const int flat = blockIdx.x * 256 + tid;    // 0..32767
    const int b = flat >> 9, t = flat & (T_LEN - 1);
    const int bq = b >> 4, bl = b & 15;
    const unsigned short* hf = xwq + ((size_t)(0 * 4 + bq) * T_LEN + t) * 16384;
    const unsigned short* hb = xwq + ((size_t)(1 * 4 + bq) * T_LEN + (T_LEN - 1 - t)) * 16384;

    float a[K_TAGS];
    #pragma unroll
    for (int k = 0; k < K_TAGS; ++k) a[k] = bdl[k];
    #pragma unroll
    for (int w = 0; w < 8; ++w) {
        #pragma unroll
        for (int q = 0; q < 4; ++q) {
            BF8 hv; hv.q = *(const uint4*)&hf[((w * 4 + q) * 16 + bl) * 8];
            #pragma unroll
            for (int nt = 0; nt < 8; ++nt) {
                const float h = bf16_to_f(hv.u[nt]);
                const float* wr = &wdl[(32 * w + 4 * nt + q) * K_TAGS];
                #pragma unroll
                for (int k = 0; k < K_TAGS; ++k) a[k] = fmaf(h, wr[k], a[k]);
            }
        }
    }
    #pragma unroll
    for (int w = 0; w < 8; ++w) {
        #pragma unroll
        for (int q = 0; q < 4; ++q) {
            BF8 hv; hv.q = *(const uint4*)&hb[((w * 4 + q) * 16 + bl) * 8];
            #pragma unroll
            for (int nt = 0; nt < 8; ++nt) {
                const float h = bf16_to_f(hv.u[nt]);
                const float* wr = &wdl[(H_DIM + 32 * w + 4 * nt + q) * K_TAGS];
                #pragma unroll
                for (int k = 0; k < K_TAGS; ++k) a[k] = fmaf(h, wr[k], a[k]);
            }
        }
    }
    float* ob = out + ((size_t)b * T_LEN + t) * K_TAGS;
    #pragma unroll
    for (int k = 0; k < K_TAGS; ++k) ob[k] = a[k];
}

// ---------------- Fallback (ws too small): R2 fp32 persistent BiLSTM, proven ----------------
__global__ __launch_bounds__(1024)
void lstm_fb(const int* __restrict__ text, const float* __restrict__ emb,
             const float* __restrict__ Wf, const float* __restrict__ Uf, const float* __restrict__ bf_,
             const float* __restrict__ Wb, const float* __restrict__ Ub, const float* __restrict__ bb,
             const float* __restrict__ Wd, float* __restrict__ out)
{
    const int bi   = blockIdx.x;
    const int d    = bi >> 5;
    const int pair = bi & 31;
    const int tid  = threadIdx.x;
    const int kc   = tid >> 8;
    const int idx  = tid & 255;

    const float* Wp = d ? Wb : Wf;
    const float* Up = d ? Ub : Uf;
    const float* bp = d ? bb : bf_;

    __shared__ __align__(16) float2 vbuf[2][384];
    __shared__ float  cspf[2][H_DIM];
    __shared__ __align__(16) float2 zp[16][256];
    __shared__ float  wdl[H_DIM * K_TAGS];
    __shared__ float  bpl[G4];

    for (int i = tid; i < H_DIM * K_TAGS; i += 1024) wdl[i] = Wd[d * H_DIM * K_TAGS + i];
    for (int i = tid; i < G4; i += 1024) bpl[i] = bp[i];
    if (tid < H_DIM) {
        vbuf[0][E_DIM + tid] = make_float2(0.0f, 0.0f);
        cspf[0][tid] = 0.0f;
        cspf[1][tid] = 0.0f;
    }
    __syncthreads();

    int cur = 0;
    for (int t = 0; t < T_LEN; ++t) {
        const int p = d ? (T_LEN - 1 - t) : t;
        const int nxt = cur ^ 1;

        if (tid < E_DIM) {
            const int tok0 = text[(pair * 2 + 0) * T_LEN + p];
            const int tok1 = text[(pair * 2 + 1) * T_LEN + p];
            vbuf[cur][tid] = make_float2(emb[(size_t)tok0 * E_DIM + tid],
                                         emb[(size_t)tok1 * E_DIM + tid]);
        }
        __syncthreads();

        {
            float2 a0 = make_float2(0.f, 0.f), a1 = a0, a2 = a0, a3 = a0;
            const int k0 = kc * 96;
            const float* wp = Wp + (size_t)k0 * G4 + 4 * idx;
            const float* up = Up + ((long)k0 - E_DIM) * G4 + 4 * idx;
            const float2* __restrict__ vb = vbuf[cur];
            #pragma unroll 8
            for (int i = 0; i < 96; ++i) {
                const int k = k0 + i;
                const float4 wv = *(const float4*)((k < E_DIM) ? wp : up);
                const float2 v = vb[k];
                a0.x = fmaf(wv.x, v.x, a0.x); a0.y = fmaf(wv.x, v.y, a0.y);
                a1.x = fmaf(wv.y, v.x, a1.x); a1.y = fmaf(wv.y, v.y, a1.y);
                a2.x = fmaf(wv.z, v.x, a2.x); a2.y = fmaf(wv.z, v.y, a2.y);
                a3.x = fmaf(wv.w, v.x, a3.x); a3.y = fmaf(wv.w, v.y, a3.y);
                wp += G4; up += G4;
            }
            zp[kc * 4 + 0][idx] = a0;
            zp[kc * 4 + 1][idx] = a1;
            zp[kc * 4 + 2][idx] = a2;
            zp[kc * 4 + 3][idx] = a3;
        }
        __syncthreads();

        if (tid < 512) {
            const int b = tid >> 8, u = tid & 255;
            const int j = u & 3, rr = u >> 2;
            float zs[4];
            #pragma unroll
            for (int g = 0; g < 4; ++g) {
                float s = bpl[g * 256 + u];
                #pragma unroll
                for (int c = 0; c < 4; ++c)
                    s += ((const float*)&zp[c * 4 + j][g * 64 + rr])[b];
                zs[g] = s;
            }
            const float co = cspf[b][u];
            const float cg = tanhf_(zs[2]);
            const float cn = sigf(zs[1]) * co + sigf(zs[0]) * cg;
            const float h  = sigf(zs[3]) * tanhf_(cn);
            cspf[b][u] = cn;
            ((float*)&vbuf[nxt][E_DIM + u])[b] = h;
        }
        __syncthreads();

        {
            const int w = tid >> 6, l = tid & 63;
            const float2* __restrict__ hb = vbuf[nxt] + E_DIM;
            for (int tau = w; tau < 2 * K_TAGS; tau += 16) {
                const int gb = tau / K_TAGS, k = tau - K_TAGS * gb;
                float v = 0.0f;
                #pragma unroll
                for (int m = 0; m < 4; ++m) {
                    const int col = l + 64 * m;
                    const float hv = ((const float*)&hb[col])[gb];
                    v += hv * wdl[col * K_TAGS + k];
                }
                for (int off = 32; off > 0; off >>= 1) v += __shfl_down(v, off);
                if (l == 0)
                    atomicAdd(&out[((size_t)(pair * 2 + gb) * T_LEN + p) * K_TAGS + k], v);
            }
        }
        cur = nxt;
    }
}

// ---------------- Kernel 2: CRF log-likelihood ----------------
__global__ __launch_bounds__(64)
void crf_kernel(const int* __restrict__ labels, const float* __restrict__ trans,
                const int* __restrict__ lens_ws, float* __restrict__ out)
{
    const int b    = blockIdx.x;
    const int lane = threadIdx.x;
    const int len  = lens_ws[b];
    const float* lb = out + (size_t)b * (T_LEN * K_TAGS);
    const int* lab  = labels + (size_t)b * T_LEN;

    float ub = 0.0f;
    for (int t = lane; t < T_LEN; t += 64) {
        if (t < len)            ub += lb[t * K_TAGS + lab[t]];
        if (t >= 1 && t < len)  ub += trans[lab[t - 1] * K_TAGS + lab[t]];
    }
    for (int off = 32; off > 0; off >>= 1) ub += __shfl_down(ub, off);

    float trc[K_TAGS];
    #pragma unroll
    for (int i = 0; i < K_TAGS; ++i)
        trc[i] = (lane < K_TAGS) ? trans[i * K_TAGS + lane] : 0.0f;
    const int kk = (lane < K_TAGS) ? lane : 0;
    float alpha = (lane < K_TAGS) ? lb[lane] : 0.0f;

    for (int t = 1; t < len; ++t) {
        float v[K_TAGS];
        float m = -1e30f;
        #pragma unroll
        for (int i = 0; i < K_TAGS; ++i) {
            float ai = __shfl(alpha, i);
            v[i] = ai + trc[i];
            m = fmaxf(m, v[i]);
        }
        float s = 0.0f;
        #pragma unroll
        for (int i = 0; i < K_TAGS; ++i) s += __expf(v[i] - m);
        float na = m + __logf(s) + lb[t * K_TAGS + kk];
        if (lane < K_TAGS) alpha = na;
    }

    float m2 = -1e30f;
    #pragma unroll
    for (int i = 0; i < K_TAGS; ++i) m2 = fmaxf(m2, __shfl(alpha, i));
    float s2 = 0.0f;
    #pragma unroll
    for (int i = 0; i < K_TAGS; ++i) s2 += __expf(__shfl(alpha, i) - m2);
    float logn = m2 + __logf(s2);

    if (lane == 0)
        out[(size_t)B_SZ * T_LEN * K_TAGS + B_SZ + b] = ub - logn;
}

extern "C" void kernel_launch(void* const* d_in, const int* in_sizes, int n_in,
                              void* d_out, int out_size, void* d_ws, size_t ws_size,
                              hipStream_t stream) {
    const int*   text   = (const int*)d_in[0];
    const int*   labels = (const int*)d_in[1];
    const float* emb    = (const float*)d_in[2];
    const float* Wf     = (const float*)d_in[3];
    const float* Uf     = (const float*)d_in[4];
    const float* bf_    = (const float*)d_in[5];
    const float* Wb     = (const float*)d_in[6];
    const float* Ub     = (const float*)d_in[7];
    const float* bb     = (const float*)d_in[8];
    const float* Wd     = (const float*)d_in[9];
    const float* bd     = (const float*)d_in[10];
    const float* trans  = (const float*)d_in[11];
    float* out = (float*)d_out;

    int* ws_head = (int*)d_ws;
    int* lens_ws = ws_head;

    unsigned short* Uc    = (unsigned short*)((char*)d_ws + 4096);            // 1 MB
    unsigned short* Wc    = (unsigned short*)((char*)d_ws + 4096 + 1048576);  // 512 KB
    float*          bperm = (float*)((char*)d_ws + 4096 + 1048576 + 524288);  // 8 KB
    unsigned short* xwq   = (unsigned short*)((char*)d_ws + 2097152);         // 128 MB (xw + hseq)
    const size_t need = 2097152 + (size_t)2 * 4 * T_LEN * 16384 * 2;

    init_kernel<<<B_SZ, 256, 0, stream>>>(text, bd, out, ws_head);
    if (ws_size >= need) {
        permute_kernel<<<dim3(1024, 2), 64, 0, stream>>>(Wf, Uf, bf_, Wb, Ub, bb, Uc, Wc, bperm);
        xw_kernel<<<dim3(T_LEN, 2), 512, 0, stream>>>(text, emb, Wc, bperm, xwq);
        rec_kernel<<<8, 512, 0, stream>>>(Uc, xwq);
        logits_kernel<<<(B_SZ * T_LEN) / 256, 256, 0, stream>>>(xwq, Wd, bd, out);
    } else {
        lstm_fb<<<64, 1024, 0, stream>>>(text, emb, Wf, Uf, bf_, Wb, Ub, bb, Wd, out);
    }
    crf_kernel<<<B_SZ, 64, 0, stream>>>(labels, trans, lens_ws, out);
}